// Round 18
// baseline (161.868 us; speedup 1.0000x reference)
//
#include <hip/hip_runtime.h>
#include <hip/hip_bf16.h>

typedef unsigned short u16;
typedef __attribute__((ext_vector_type(8))) short bf16x8;
typedef __attribute__((ext_vector_type(4))) float f32x4;

#define N_MEM_C 65536
#define NNODES_C 50000
#define DDIM 128
#define TIL(t) ((t) * 16384)

// bf16 [n][k] weight tiles (128x128), PRE-SWIZZLED:
// 0: msg_W1[0:128]^T (vi)   1: msg_W1[256:384]^T (vj)   2: msg_W2^T
// 3: 0.5*hid_W1[0:128]^T (aggr, pre-scaled) 4: hid_W1[128:256]^T
// 5: (int_W @ hid_W1[256:384])^T    6: hid_W2^T
__device__ __align__(16) u16 g_WT[7 * 16384];
__device__ __align__(16) float g_relW[500 * 128];
__device__ __align__(16) float g_qsumM[64 * 128];
__device__ __align__(16) float g_qsumH[64 * 128];
__device__ __align__(16) u16 g_hb[(size_t)N_MEM_C * DDIM];
__device__ __align__(16) u16 g_ub[(size_t)NNODES_C * DDIM];
// precomputed GEMM tables (bf16) + edge-phase output
__device__ __align__(16) u16 g_H0[(size_t)N_MEM_C * DDIM];    // hidden@W1_vi
__device__ __align__(16) u16 g_Hvj[(size_t)N_MEM_C * DDIM];   // hidden@W1_vj + msg_b1
__device__ __align__(16) u16 g_Hm[(size_t)N_MEM_C * DDIM];    // hidden@hidW1_hid + hid_b1
__device__ __align__(16) u16 g_U5[(size_t)50048 * DDIM];      // uncon@Weff (padded)
__device__ __align__(16) u16 g_aggr[(size_t)N_MEM_C * DDIM];  // sum tanh(message)

#define SBAR() do { asm volatile("" ::: "memory"); __builtin_amdgcn_s_barrier(); \
                    asm volatile("" ::: "memory"); } while (0)
#define WAIT_VM0() asm volatile("s_waitcnt vmcnt(0)" ::: "memory")
#define WAIT_LG0() asm volatile("s_waitcnt lgkmcnt(0)" ::: "memory")

__device__ __forceinline__ u16 f2bf_s(float f) {
  __hip_bfloat16 h = __float2bfloat16(f);
  u16 u; __builtin_memcpy(&u, &h, 2);
  return u;
}
__device__ __forceinline__ unsigned pk2(float a, float b) {
  __hip_bfloat162 h = __float22bfloat162_rn(make_float2(a, b));
  unsigned u; __builtin_memcpy(&u, &h, 4);
  return u;
}
__device__ __forceinline__ float bf2f(u16 u) {
  unsigned v = ((unsigned)u) << 16;
  float f; __builtin_memcpy(&f, &v, 4);
  return f;
}
__device__ __forceinline__ float fast_tanh(float x) {
  float e = __expf(2.0f * x);
  return 1.0f - 2.0f / (e + 1.0f);
}
__device__ __forceinline__ int swz_off(int r, int c) {
  return r * 128 + ((((c >> 3) ^ (r & 7)) << 3) | (c & 7));
}

// ================= prep 1: conversions + small tables =================
extern "C" __global__ void prep_all(const float* __restrict__ hidden,
                                    const float* __restrict__ uncon,
                                    const float* __restrict__ msg_W1,
                                    const float* __restrict__ msg_W2,
                                    const float* __restrict__ hid_W1,
                                    const float* __restrict__ hid_W2,
                                    const float* __restrict__ int_W,
                                    const float* __restrict__ rel_table,
                                    const float* __restrict__ qh,
                                    const float* __restrict__ qr) {
  int bid = blockIdx.x;
  if (bid < 7221) {
    const size_t NH = (size_t)N_MEM_C * DDIM / 8;
    size_t i = (size_t)bid * 256 + threadIdx.x;
    const float* src; u16* dst; size_t o;
    if (i < NH) { src = hidden; dst = g_hb; o = i; }
    else { src = uncon; dst = g_ub; o = i - NH; }
    const float4* p = (const float4*)(src + o * 8);
    float4 a = p[0], b = p[1];
    *(uint4*)(dst + o * 8) =
        make_uint4(pk2(a.x, a.y), pk2(a.z, a.w), pk2(b.x, b.y), pk2(b.z, b.w));
  } else if (bid < 7605) {                // transpose+convert+SWIZZLE 6 tiles
    int i = (bid - 7221) * 256 + threadIdx.x;
    int t = i >> 14, idx = i & 16383;
    int n = idx >> 7, k = idx & 127;
    const float* src; int dst; float sc = 1.0f;
    switch (t) {
      case 0:  src = msg_W1;             dst = TIL(0); break;
      case 1:  src = msg_W1 + 256 * 128; dst = TIL(1); break;
      case 2:  src = msg_W2;             dst = TIL(2); break;
      case 3:  src = hid_W1;             dst = TIL(3); sc = 0.5f; break;  // fold 0.5*aggr
      case 4:  src = hid_W1 + 128 * 128; dst = TIL(4); break;
      default: src = hid_W2;             dst = TIL(6); break;
    }
    g_WT[dst + swz_off(n, k)] = f2bf_s(sc * src[k * 128 + n]);
  } else if (bid < 7669) {                // Weff = int_W @ hid_W1[256:384] (swz)
    int i = (bid - 7605) * 256 + threadIdx.x;
    int n = i & 127, q = i >> 7;
    float s = 0.f;
    for (int p = 0; p < 128; ++p)
      s += int_W[q * 128 + p] * hid_W1[(256 + p) * 128 + n];
    g_WT[TIL(5) + swz_off(n, q)] = f2bf_s(s);
  } else if (bid < 7919) {                // relW
    int i = (bid - 7669) * 256 + threadIdx.x;
    int r = i >> 7, n = i & 127;
    float s = 0.f;
    for (int k = 0; k < 128; ++k)
      s += rel_table[r * 128 + k] * msg_W1[(128 + k) * 128 + n];
    g_relW[i] = s;
  } else {                                // qsum (both MLPs)
    int i = (bid - 7919) * 256 + threadIdx.x;
    int g = i >> 7, n = i & 127;
    float sM = 0.f, sH = 0.f;
    for (int k = 0; k < 128; ++k) {
      float h = qh[g * 128 + k], r = qr[g * 128 + k];
      sM += h * msg_W1[(384 + k) * 128 + n] + r * msg_W1[(512 + k) * 128 + n];
      sH += h * hid_W1[(384 + k) * 128 + n] + r * hid_W1[(512 + k) * 128 + n];
    }
    g_qsumM[i] = sM;
    g_qsumH[i] = sH;
  }
}

// ---- staging helpers ----
__device__ __forceinline__ void gload_rows8(u16* lds_tile, const u16* __restrict__ gsrc,
                                            const int* idxArr, int base, int maxIdx,
                                            int wid, int lane) {
  int rsub = lane >> 4, s = lane & 15;
#pragma unroll
  for (int k = 0; k < 4; ++k) {
    int r = wid * 16 + k * 4 + rsub;
    int idx = idxArr ? idxArr[r] : min(base + r, maxIdx);
    const u16* gp = gsrc + (size_t)idx * DDIM + ((s ^ (r & 7)) << 3);
    u16* lp = lds_tile + (wid * 16 + k * 4) * 128;
    __builtin_amdgcn_global_load_lds((const __attribute__((address_space(1))) void*)gp,
                                     (__attribute__((address_space(3))) void*)lp,
                                     16, 0, 0);
  }
}
__device__ __forceinline__ void gload_lin8(u16* lds_tile, const u16* __restrict__ gsrc,
                                           int wid, int lane) {
#pragma unroll
  for (int k = 0; k < 4; ++k) {
    int off = (wid * 4 + k) * 512;
    __builtin_amdgcn_global_load_lds(
        (const __attribute__((address_space(1))) void*)(gsrc + off + lane * 8),
        (__attribute__((address_space(3))) void*)(lds_tile + off), 16, 0, 0);
  }
}
__device__ __forceinline__ void gload_lin4(u16* lds_tile, const u16* __restrict__ gsrc,
                                           int wid, int lane) {
#pragma unroll
  for (int k = 0; k < 8; ++k) {
    int off = (wid * 8 + k) * 512;
    __builtin_amdgcn_global_load_lds(
        (const __attribute__((address_space(1))) void*)(gsrc + off + lane * 8),
        (__attribute__((address_space(3))) void*)(lds_tile + off), 16, 0, 0);
  }
}

// A(128x128 swz) @ W(128x128 swz)^T, 8 waves 2x4, 64x32/wave
__device__ __forceinline__ void gemmS128(const u16* A, const u16* W,
                                         f32x4 (&acc)[4][2], int wr, int wc, int l16, int l4) {
  __builtin_amdgcn_s_setprio(1);
#pragma unroll
  for (int ks = 0; ks < 4; ++ks) {
    int gsl = ks * 4 + l4;
    bf16x8 av[4], bv[2];
#pragma unroll
    for (int nr = 0; nr < 2; ++nr) {
      int rW = wc * 32 + nr * 16 + l16;
      bv[nr] = *(const bf16x8*)&W[rW * 128 + ((gsl ^ (rW & 7)) << 3)];
    }
#pragma unroll
    for (int mr = 0; mr < 4; ++mr) {
      int rA = wr * 64 + mr * 16 + l16;
      av[mr] = *(const bf16x8*)&A[rA * 128 + ((gsl ^ (rA & 7)) << 3)];
    }
#pragma unroll
    for (int mr = 0; mr < 4; ++mr)
#pragma unroll
      for (int nr = 0; nr < 2; ++nr)
        acc[mr][nr] = __builtin_amdgcn_mfma_f32_16x16x32_bf16(av[mr], bv[nr], acc[mr][nr], 0, 0, 0);
  }
  __builtin_amdgcn_s_setprio(0);
}

// A(64x128 swz) @ W(128x128 swz)^T, 4 waves 2x2, 32x64/wave
__device__ __forceinline__ void gemmS64(const u16* A, const u16* W,
                                        f32x4 (&acc)[2][4], int wr, int wc, int l16, int l4) {
  __builtin_amdgcn_s_setprio(1);
#pragma unroll
  for (int ks = 0; ks < 4; ++ks) {
    int gsl = ks * 4 + l4;
    bf16x8 av[2], bv[4];
#pragma unroll
    for (int nr = 0; nr < 4; ++nr) {
      int rW = wc * 64 + nr * 16 + l16;
      bv[nr] = *(const bf16x8*)&W[rW * 128 + ((gsl ^ (rW & 7)) << 3)];
    }
#pragma unroll
    for (int mr = 0; mr < 2; ++mr) {
      int rA = wr * 32 + mr * 16 + l16;
      av[mr] = *(const bf16x8*)&A[rA * 128 + ((gsl ^ (rA & 7)) << 3)];
    }
#pragma unroll
    for (int mr = 0; mr < 2; ++mr)
#pragma unroll
      for (int nr = 0; nr < 4; ++nr)
        acc[mr][nr] = __builtin_amdgcn_mfma_f32_16x16x32_bf16(av[mr], bv[nr], acc[mr][nr], 0, 0, 0);
  }
  __builtin_amdgcn_s_setprio(0);
}

// ================= prep 2: dense GEMM tables H0/Hvj/Hm/U5 =================
extern "C" __global__ __launch_bounds__(512, 2) void prep_tables(
    const float* __restrict__ msg_b1, const float* __restrict__ hid_b1) {
  int bid = blockIdx.x;
  const u16* src; const u16* W; u16* dst; const float* bias = nullptr;
  int row0, maxIdx, nrows;
  if (bid < 512)       { src = g_hb; W = g_WT + TIL(0); dst = g_H0;  row0 = bid * 128;          maxIdx = N_MEM_C - 1; nrows = N_MEM_C; }
  else if (bid < 1024) { src = g_hb; W = g_WT + TIL(1); dst = g_Hvj; row0 = (bid - 512) * 128;  maxIdx = N_MEM_C - 1; nrows = N_MEM_C; bias = msg_b1; }
  else if (bid < 1536) { src = g_hb; W = g_WT + TIL(4); dst = g_Hm;  row0 = (bid - 1024) * 128; maxIdx = N_MEM_C - 1; nrows = N_MEM_C; bias = hid_b1; }
  else                 { src = g_ub; W = g_WT + TIL(5); dst = g_U5;  row0 = (bid - 1536) * 128; maxIdx = NNODES_C - 1; nrows = 50048; }

  __shared__ u16 sA[16384], sW[16384];
  const int tid = threadIdx.x, lane = tid & 63, wid = tid >> 6;
  const int wr = wid >> 2, wc = wid & 3, l16 = lane & 15, l4 = lane >> 4;

  gload_rows8(sA, src, nullptr, row0, maxIdx, wid, lane);
  gload_lin8(sW, W, wid, lane);
  WAIT_VM0(); SBAR();

  const f32x4 zero4 = {0.f, 0.f, 0.f, 0.f};
  f32x4 acc[4][2];
#pragma unroll
  for (int a = 0; a < 4; ++a)
#pragma unroll
    for (int b = 0; b < 2; ++b) acc[a][b] = zero4;
  gemmS128(sA, sW, acc, wr, wc, l16, l4);

#pragma unroll
  for (int nr = 0; nr < 2; ++nr) {
    int col = wc * 32 + nr * 16 + l16;
    float bv = bias ? bias[col] : 0.f;
#pragma unroll
    for (int mr = 0; mr < 4; ++mr)
#pragma unroll
      for (int i = 0; i < 4; ++i) {
        int row = row0 + wr * 64 + mr * 16 + l4 * 4 + i;
        if (row < nrows)
          dst[(size_t)row * 128 + col] = f2bf_s(acc[mr][nr][i] + bv);
      }
  }
}

// ================= K1: edge phase (gather-add layer1 + one gemm) =============
extern "C" __global__ __launch_bounds__(256, 2) void edge_flow(
    const int* __restrict__ seen_edges, const float* __restrict__ msg_b2) {
  __shared__ u16 sH[64 * 128];      // 16 KB (swizzled)
  __shared__ u16 sW2[16384];        // 32 KB
  __shared__ int sEg[4][64], sRel[4][64], sVi[4][64];

  const int tid = threadIdx.x;
  const int lane = tid & 63, wid = tid >> 6;
  const int wr = wid >> 1, wc = wid & 1;     // 2x2 grid, 32x64 per wave
  const int l16 = lane & 15, l4 = lane >> 4;
  const int j0 = blockIdx.x * 64;
  const int pr = tid >> 2, pcs = (tid & 3) * 32;   // h-build ownership

  float mb2v[4];
#pragma unroll
  for (int nr = 0; nr < 4; ++nr) mb2v[nr] = msg_b2[wc * 64 + nr * 16 + l16];

  gload_lin4(sW2, g_WT + TIL(2), wid, lane);
  {
    int t = tid >> 6, r = tid & 63;
    int e = j0 + r + t * N_MEM_C;
    const int4* se = (const int4*)seen_edges + (size_t)e * 2;
    int4 lo = se[0], hi = se[1];
    sEg[t][r] = min(max(lo.x, 0), 63);
    sRel[t][r] = min(max(lo.w, 0), 499);
    sVi[t][r] = min(max(hi.z, 0), N_MEM_C - 1);
  }
  WAIT_LG0(); WAIT_VM0(); SBAR();       // W2 + indices resident

  const f32x4 zero4 = {0.f, 0.f, 0.f, 0.f};
  f32x4 aggr[2][4];
#pragma unroll
  for (int a = 0; a < 2; ++a)
#pragma unroll
    for (int b = 0; b < 4; ++b) aggr[a][b] = zero4;

#pragma unroll 1
  for (int t = 0; t < 4; ++t) {
    // h = lrelu(H0[vi] + Hvj[j] + relW[rel] + qsumM[eg]) -> sH (swizzled)
    const uint4* p0 = (const uint4*)(g_H0 + (size_t)sVi[t][pr] * 128 + pcs);
    const uint4* pv = (const uint4*)(g_Hvj + (size_t)(j0 + pr) * 128 + pcs);
    const float4* prl = (const float4*)(g_relW + sRel[t][pr] * 128 + pcs);
    const float4* pq = (const float4*)(g_qsumM + sEg[t][pr] * 128 + pcs);
#pragma unroll
    for (int m = 0; m < 4; ++m) {
      uint4 a0 = p0[m], av_ = pv[m];
      float4 r0 = prl[2 * m], r1 = prl[2 * m + 1];
      float4 q0 = pq[2 * m], q1 = pq[2 * m + 1];
      u16 h0[8], hv[8];
      __builtin_memcpy(h0, &a0, 16); __builtin_memcpy(hv, &av_, 16);
      float v[8];
      v[0] = bf2f(h0[0]) + bf2f(hv[0]) + r0.x + q0.x;
      v[1] = bf2f(h0[1]) + bf2f(hv[1]) + r0.y + q0.y;
      v[2] = bf2f(h0[2]) + bf2f(hv[2]) + r0.z + q0.z;
      v[3] = bf2f(h0[3]) + bf2f(hv[3]) + r0.w + q0.w;
      v[4] = bf2f(h0[4]) + bf2f(hv[4]) + r1.x + q1.x;
      v[5] = bf2f(h0[5]) + bf2f(hv[5]) + r1.y + q1.y;
      v[6] = bf2f(h0[6]) + bf2f(hv[6]) + r1.z + q1.z;
      v[7] = bf2f(h0[7]) + bf2f(hv[7]) + r1.w + q1.w;
#pragma unroll
      for (int p = 0; p < 8; ++p) v[p] = (v[p] >= 0.f) ? v[p] : 0.2f * v[p];
      *(uint4*)&sH[swz_off(pr, pcs + 8 * m)] =
          make_uint4(pk2(v[0], v[1]), pk2(v[2], v[3]), pk2(v[4], v[5]), pk2(v[6], v[7]));
    }
    WAIT_LG0(); SBAR();                  // h writes DRAINED then published (r17 bug fix)

    f32x4 acc2[2][4];
#pragma unroll
    for (int a = 0; a < 2; ++a)
#pragma unroll
      for (int b = 0; b < 4; ++b) acc2[a][b] = zero4;
    gemmS64(sH, sW2, acc2, wr, wc, l16, l4);
#pragma unroll
    for (int mr = 0; mr < 2; ++mr)
#pragma unroll
      for (int nr = 0; nr < 4; ++nr)
#pragma unroll
        for (int i = 0; i < 4; ++i)
          aggr[mr][nr][i] += fast_tanh(acc2[mr][nr][i] + mb2v[nr]);
    WAIT_LG0(); SBAR();                  // all reads consumed before overwrite
  }

  // write aggr rows (bf16)
#pragma unroll
  for (int mr = 0; mr < 2; ++mr)
#pragma unroll
    for (int nr = 0; nr < 4; ++nr)
#pragma unroll
      for (int i = 0; i < 4; ++i) {
        int row = j0 + wr * 32 + mr * 16 + l4 * 4 + i;
        int col = wc * 64 + nr * 16 + l16;
        g_aggr[(size_t)row * 128 + col] = f2bf_s(aggr[mr][nr][i]);
      }
}

// ================= K2: update phase (3 spans) =================
extern "C" __global__ __launch_bounds__(512, 2) void update_flow(
    const int* __restrict__ memorized, const float* __restrict__ node_att,
    const float* __restrict__ hid_b2, float* __restrict__ out) {
  __shared__ u16 sA[16384], sH[16384];   // aggr rows / h tile
  __shared__ u16 sW3[16384], sW2[16384];
  __shared__ int sMeg[128], sMvm[128];
  __shared__ float sNA[128];

  const int tid = threadIdx.x;
  const int lane = tid & 63, wid = tid >> 6;
  const int wr = wid >> 2, wc = wid & 3;   // 2x4 grid, 64x32 per wave
  const int l16 = lane & 15, l4 = lane >> 4;
  const int j0 = blockIdx.x * 128;

  float hb2v[2];
#pragma unroll
  for (int nr = 0; nr < 2; ++nr) hb2v[nr] = hid_b2[wc * 32 + nr * 16 + l16];

  gload_rows8(sA, g_aggr, nullptr, j0, N_MEM_C - 1, wid, lane);
  gload_lin8(sW3, g_WT + TIL(3), wid, lane);
  gload_lin8(sW2, g_WT + TIL(6), wid, lane);
  if (tid < 128) {
    int2 mn = ((const int2*)memorized)[j0 + tid];
    int eg = min(max(mn.x, 0), 63);
    int vm = min(max(mn.y, 0), NNODES_C - 1);
    sMeg[tid] = eg; sMvm[tid] = vm;
    sNA[tid] = node_att[(size_t)eg * NNODES_C + vm];
  }
  WAIT_LG0(); WAIT_VM0(); SBAR();

  const f32x4 zero4 = {0.f, 0.f, 0.f, 0.f};
  f32x4 accU[4][2];
#pragma unroll
  for (int a = 0; a < 4; ++a)
#pragma unroll
    for (int b = 0; b < 2; ++b) accU[a][b] = zero4;
  gemmS128(sA, sW3, accU, wr, wc, l16, l4);    // aggr @ (0.5*hidW1_aggr)

  // gather-add: Hm[j] + na*U5[vm] + qsumH[eg]
#pragma unroll
  for (int mr = 0; mr < 4; ++mr)
#pragma unroll
    for (int i = 0; i < 4; ++i) {
      int r = wr * 64 + mr * 16 + l4 * 4 + i;
      float na = sNA[r];
      const u16* pM = g_Hm + (size_t)(j0 + r) * 128;
      const u16* pU = g_U5 + (size_t)sMvm[r] * 128;
      const float* pQ = g_qsumH + sMeg[r] * 128;
#pragma unroll
      for (int nr = 0; nr < 2; ++nr) {
        int c = wc * 32 + nr * 16 + l16;
        accU[mr][nr][i] += bf2f(pM[c]) + na * bf2f(pU[c]) + pQ[c];
      }
    }
  // h = lrelu(accU) -> sH (swizzled)
#pragma unroll
  for (int mr = 0; mr < 4; ++mr)
#pragma unroll
    for (int nr = 0; nr < 2; ++nr)
#pragma unroll
      for (int i = 0; i < 4; ++i) {
        float v = accU[mr][nr][i];
        v = (v >= 0.f) ? v : 0.2f * v;
        int r = wr * 64 + mr * 16 + l4 * 4 + i;
        sH[swz_off(r, wc * 32 + nr * 16 + l16)] = f2bf_s(v);
      }
  WAIT_LG0(); SBAR();

  f32x4 accF[4][2];
#pragma unroll
  for (int a = 0; a < 4; ++a)
#pragma unroll
    for (int b = 0; b < 2; ++b) accF[a][b] = zero4;
  gemmS128(sH, sW2, accF, wr, wc, l16, l4);

#pragma unroll
  for (int mr = 0; mr < 4; ++mr)
#pragma unroll
    for (int nr = 0; nr < 2; ++nr)
#pragma unroll
      for (int i = 0; i < 4; ++i) {
        int row = j0 + wr * 64 + mr * 16 + l4 * 4 + i;
        int col = wc * 32 + nr * 16 + l16;
        size_t o = (size_t)row * DDIM + col;
        out[o] = bf2f(g_hb[o]) + fast_tanh(accF[mr][nr][i] + hb2v[nr]);
      }
}

extern "C" void kernel_launch(void* const* d_in, const int* in_sizes, int n_in,
                              void* d_out, int out_size, void* d_ws, size_t ws_size,
                              hipStream_t stream) {
  (void)in_sizes; (void)n_in; (void)out_size; (void)d_ws; (void)ws_size;
  const float* hidden       = (const float*)d_in[0];
  const int*   seen_edges   = (const int*)d_in[1];
  const int*   memorized    = (const int*)d_in[2];
  const float* node_att     = (const float*)d_in[3];
  const float* hidden_uncon = (const float*)d_in[4];
  const float* qh           = (const float*)d_in[5];
  const float* qr           = (const float*)d_in[6];
  const float* rel_table    = (const float*)d_in[7];
  const float* msg_W1       = (const float*)d_in[8];
  const float* msg_b1       = (const float*)d_in[9];
  const float* msg_W2       = (const float*)d_in[10];
  const float* msg_b2       = (const float*)d_in[11];
  const float* hid_W1       = (const float*)d_in[12];
  const float* hid_b1       = (const float*)d_in[13];
  const float* hid_W2       = (const float*)d_in[14];
  const float* hid_b2       = (const float*)d_in[15];
  const float* int_W        = (const float*)d_in[16];

  prep_all<<<dim3(7951), dim3(256), 0, stream>>>(
      hidden, hidden_uncon, msg_W1, msg_W2, hid_W1, hid_W2, int_W,
      rel_table, qh, qr);
  prep_tables<<<dim3(1927), dim3(512), 0, stream>>>(msg_b1, hid_b1);
  edge_flow<<<dim3(N_MEM_C / 64), dim3(256), 0, stream>>>(seen_edges, msg_b2);
  update_flow<<<dim3(N_MEM_C / 128), dim3(512), 0, stream>>>(
      memorized, node_att, hid_b2, (float*)d_out);
}

// Round 19
// 141.914 us; speedup vs baseline: 1.1406x; 1.1406x over previous
//
#include <hip/hip_runtime.h>
#include <hip/hip_bf16.h>

typedef unsigned short u16;
typedef __attribute__((ext_vector_type(8))) short bf16x8;
typedef __attribute__((ext_vector_type(4))) float f32x4;

#define N_MEM_C 65536
#define NNODES_C 50000
#define DDIM 128
#define TIL(t) ((t) * 16384)

// bf16 [n][k] weight tiles (128x128), PRE-SWIZZLED:
// 0: msg_W1[0:128]^T (vi)   1: msg_W1[256:384]^T (vj)   2: msg_W2^T
// 3: 0.5*hid_W1[0:128]^T (aggr, pre-scaled) 4: hid_W1[128:256]^T
// 5: (int_W @ hid_W1[256:384])^T    6: hid_W2^T
__device__ __align__(16) u16 g_WT[7 * 16384];
__device__ __align__(16) float g_relW[500 * 128];
__device__ __align__(16) float g_qsumM[64 * 128];
__device__ __align__(16) float g_qsumH[64 * 128];
__device__ __align__(16) u16 g_hb[(size_t)N_MEM_C * DDIM];
__device__ __align__(16) u16 g_ub[(size_t)NNODES_C * DDIM];
// precomputed GEMM tables (bf16) + edge-phase output
__device__ __align__(16) u16 g_H0[(size_t)N_MEM_C * DDIM];    // hidden@W1_vi
__device__ __align__(16) u16 g_Hvj[(size_t)N_MEM_C * DDIM];   // hidden@W1_vj + msg_b1
__device__ __align__(16) u16 g_Hm[(size_t)N_MEM_C * DDIM];    // hidden@hidW1_hid + hid_b1
__device__ __align__(16) u16 g_U5[(size_t)50048 * DDIM];      // uncon@Weff (padded)
__device__ __align__(16) u16 g_aggr[(size_t)N_MEM_C * DDIM];  // sum tanh(message)

#define SBAR() do { asm volatile("" ::: "memory"); __builtin_amdgcn_s_barrier(); \
                    asm volatile("" ::: "memory"); } while (0)
#define WAIT_VM0() asm volatile("s_waitcnt vmcnt(0)" ::: "memory")
#define WAIT_LG0() asm volatile("s_waitcnt lgkmcnt(0)" ::: "memory")

__device__ __forceinline__ u16 f2bf_s(float f) {
  __hip_bfloat16 h = __float2bfloat16(f);
  u16 u; __builtin_memcpy(&u, &h, 2);
  return u;
}
__device__ __forceinline__ unsigned pk2(float a, float b) {
  __hip_bfloat162 h = __float22bfloat162_rn(make_float2(a, b));
  unsigned u; __builtin_memcpy(&u, &h, 4);
  return u;
}
__device__ __forceinline__ float bf2f(u16 u) {
  unsigned v = ((unsigned)u) << 16;
  float f; __builtin_memcpy(&f, &v, 4);
  return f;
}
__device__ __forceinline__ float fast_tanh(float x) {
  float e = __expf(2.0f * x);
  return 1.0f - 2.0f / (e + 1.0f);
}
__device__ __forceinline__ int swz_off(int r, int c) {
  return r * 128 + ((((c >> 3) ^ (r & 7)) << 3) | (c & 7));
}

// ================= prep 1: conversions + small tables (unchanged r18) ========
extern "C" __global__ void prep_all(const float* __restrict__ hidden,
                                    const float* __restrict__ uncon,
                                    const float* __restrict__ msg_W1,
                                    const float* __restrict__ msg_W2,
                                    const float* __restrict__ hid_W1,
                                    const float* __restrict__ hid_W2,
                                    const float* __restrict__ int_W,
                                    const float* __restrict__ rel_table,
                                    const float* __restrict__ qh,
                                    const float* __restrict__ qr) {
  int bid = blockIdx.x;
  if (bid < 7221) {
    const size_t NH = (size_t)N_MEM_C * DDIM / 8;
    size_t i = (size_t)bid * 256 + threadIdx.x;
    const float* src; u16* dst; size_t o;
    if (i < NH) { src = hidden; dst = g_hb; o = i; }
    else { src = uncon; dst = g_ub; o = i - NH; }
    const float4* p = (const float4*)(src + o * 8);
    float4 a = p[0], b = p[1];
    *(uint4*)(dst + o * 8) =
        make_uint4(pk2(a.x, a.y), pk2(a.z, a.w), pk2(b.x, b.y), pk2(b.z, b.w));
  } else if (bid < 7605) {                // transpose+convert+SWIZZLE 6 tiles
    int i = (bid - 7221) * 256 + threadIdx.x;
    int t = i >> 14, idx = i & 16383;
    int n = idx >> 7, k = idx & 127;
    const float* src; int dst; float sc = 1.0f;
    switch (t) {
      case 0:  src = msg_W1;             dst = TIL(0); break;
      case 1:  src = msg_W1 + 256 * 128; dst = TIL(1); break;
      case 2:  src = msg_W2;             dst = TIL(2); break;
      case 3:  src = hid_W1;             dst = TIL(3); sc = 0.5f; break;
      case 4:  src = hid_W1 + 128 * 128; dst = TIL(4); break;
      default: src = hid_W2;             dst = TIL(6); break;
    }
    g_WT[dst + swz_off(n, k)] = f2bf_s(sc * src[k * 128 + n]);
  } else if (bid < 7669) {                // Weff = int_W @ hid_W1[256:384] (swz)
    int i = (bid - 7605) * 256 + threadIdx.x;
    int n = i & 127, q = i >> 7;
    float s = 0.f;
    for (int p = 0; p < 128; ++p)
      s += int_W[q * 128 + p] * hid_W1[(256 + p) * 128 + n];
    g_WT[TIL(5) + swz_off(n, q)] = f2bf_s(s);
  } else if (bid < 7919) {                // relW
    int i = (bid - 7669) * 256 + threadIdx.x;
    int r = i >> 7, n = i & 127;
    float s = 0.f;
    for (int k = 0; k < 128; ++k)
      s += rel_table[r * 128 + k] * msg_W1[(128 + k) * 128 + n];
    g_relW[i] = s;
  } else {                                // qsum (both MLPs)
    int i = (bid - 7919) * 256 + threadIdx.x;
    int g = i >> 7, n = i & 127;
    float sM = 0.f, sH = 0.f;
    for (int k = 0; k < 128; ++k) {
      float h = qh[g * 128 + k], r = qr[g * 128 + k];
      sM += h * msg_W1[(384 + k) * 128 + n] + r * msg_W1[(512 + k) * 128 + n];
      sH += h * hid_W1[(384 + k) * 128 + n] + r * hid_W1[(512 + k) * 128 + n];
    }
    g_qsumM[i] = sM;
    g_qsumH[i] = sH;
  }
}

// ---- staging helpers (unchanged) ----
__device__ __forceinline__ void gload_rows8(u16* lds_tile, const u16* __restrict__ gsrc,
                                            const int* idxArr, int base, int maxIdx,
                                            int wid, int lane) {
  int rsub = lane >> 4, s = lane & 15;
#pragma unroll
  for (int k = 0; k < 4; ++k) {
    int r = wid * 16 + k * 4 + rsub;
    int idx = idxArr ? idxArr[r] : min(base + r, maxIdx);
    const u16* gp = gsrc + (size_t)idx * DDIM + ((s ^ (r & 7)) << 3);
    u16* lp = lds_tile + (wid * 16 + k * 4) * 128;
    __builtin_amdgcn_global_load_lds((const __attribute__((address_space(1))) void*)gp,
                                     (__attribute__((address_space(3))) void*)lp,
                                     16, 0, 0);
  }
}
__device__ __forceinline__ void gload_lin8(u16* lds_tile, const u16* __restrict__ gsrc,
                                           int wid, int lane) {
#pragma unroll
  for (int k = 0; k < 4; ++k) {
    int off = (wid * 4 + k) * 512;
    __builtin_amdgcn_global_load_lds(
        (const __attribute__((address_space(1))) void*)(gsrc + off + lane * 8),
        (__attribute__((address_space(3))) void*)(lds_tile + off), 16, 0, 0);
  }
}
__device__ __forceinline__ void gload_lin4(u16* lds_tile, const u16* __restrict__ gsrc,
                                           int wid, int lane) {
#pragma unroll
  for (int k = 0; k < 8; ++k) {
    int off = (wid * 8 + k) * 512;
    __builtin_amdgcn_global_load_lds(
        (const __attribute__((address_space(1))) void*)(gsrc + off + lane * 8),
        (__attribute__((address_space(3))) void*)(lds_tile + off), 16, 0, 0);
  }
}

// A(128x128 swz) @ W(128x128 swz)^T, 8 waves 2x4, 64x32/wave
__device__ __forceinline__ void gemmS128(const u16* A, const u16* W,
                                         f32x4 (&acc)[4][2], int wr, int wc, int l16, int l4) {
  __builtin_amdgcn_s_setprio(1);
#pragma unroll
  for (int ks = 0; ks < 4; ++ks) {
    int gsl = ks * 4 + l4;
    bf16x8 av[4], bv[2];
#pragma unroll
    for (int nr = 0; nr < 2; ++nr) {
      int rW = wc * 32 + nr * 16 + l16;
      bv[nr] = *(const bf16x8*)&W[rW * 128 + ((gsl ^ (rW & 7)) << 3)];
    }
#pragma unroll
    for (int mr = 0; mr < 4; ++mr) {
      int rA = wr * 64 + mr * 16 + l16;
      av[mr] = *(const bf16x8*)&A[rA * 128 + ((gsl ^ (rA & 7)) << 3)];
    }
#pragma unroll
    for (int mr = 0; mr < 4; ++mr)
#pragma unroll
      for (int nr = 0; nr < 2; ++nr)
        acc[mr][nr] = __builtin_amdgcn_mfma_f32_16x16x32_bf16(av[mr], bv[nr], acc[mr][nr], 0, 0, 0);
  }
  __builtin_amdgcn_s_setprio(0);
}

// A(64x128 swz) @ W(128x128 swz)^T, 4 waves 2x2, 32x64/wave
__device__ __forceinline__ void gemmS64(const u16* A, const u16* W,
                                        f32x4 (&acc)[2][4], int wr, int wc, int l16, int l4) {
  __builtin_amdgcn_s_setprio(1);
#pragma unroll
  for (int ks = 0; ks < 4; ++ks) {
    int gsl = ks * 4 + l4;
    bf16x8 av[2], bv[4];
#pragma unroll
    for (int nr = 0; nr < 4; ++nr) {
      int rW = wc * 64 + nr * 16 + l16;
      bv[nr] = *(const bf16x8*)&W[rW * 128 + ((gsl ^ (rW & 7)) << 3)];
    }
#pragma unroll
    for (int mr = 0; mr < 2; ++mr) {
      int rA = wr * 32 + mr * 16 + l16;
      av[mr] = *(const bf16x8*)&A[rA * 128 + ((gsl ^ (rA & 7)) << 3)];
    }
#pragma unroll
    for (int mr = 0; mr < 2; ++mr)
#pragma unroll
      for (int nr = 0; nr < 4; ++nr)
        acc[mr][nr] = __builtin_amdgcn_mfma_f32_16x16x32_bf16(av[mr], bv[nr], acc[mr][nr], 0, 0, 0);
  }
  __builtin_amdgcn_s_setprio(0);
}

__device__ __forceinline__ void gemm_store(const u16* sA, const u16* sW, u16* dst,
                                           const float* bias, int row0, int nrows,
                                           int wr, int wc, int l16, int l4) {
  const f32x4 zero4 = {0.f, 0.f, 0.f, 0.f};
  f32x4 acc[4][2];
#pragma unroll
  for (int a = 0; a < 4; ++a)
#pragma unroll
    for (int b = 0; b < 2; ++b) acc[a][b] = zero4;
  gemmS128(sA, sW, acc, wr, wc, l16, l4);
#pragma unroll
  for (int nr = 0; nr < 2; ++nr) {
    int col = wc * 32 + nr * 16 + l16;
    float bv = bias ? bias[col] : 0.f;
#pragma unroll
    for (int mr = 0; mr < 4; ++mr)
#pragma unroll
      for (int i = 0; i < 4; ++i) {
        int row = row0 + wr * 64 + mr * 16 + l4 * 4 + i;
        if (row < nrows)
          dst[(size_t)row * 128 + col] = f2bf_s(acc[mr][nr][i] + bv);
      }
  }
}

// ========== prep 2: GEMM tables — A loaded ONCE, 3 gemms (H0,Hvj,Hm) ==========
extern "C" __global__ __launch_bounds__(512, 2) void prep_tables(
    const float* __restrict__ msg_b1, const float* __restrict__ hid_b1) {
  __shared__ u16 sA[16384], sW[16384];
  const int tid = threadIdx.x, lane = tid & 63, wid = tid >> 6;
  const int wr = wid >> 2, wc = wid & 3, l16 = lane & 15, l4 = lane >> 4;
  int bid = blockIdx.x;

  if (bid < 512) {                        // hidden row-chunk -> H0, Hvj, Hm
    int row0 = bid * 128;
    gload_rows8(sA, g_hb, nullptr, row0, N_MEM_C - 1, wid, lane);
    gload_lin8(sW, g_WT + TIL(0), wid, lane);
    WAIT_VM0(); SBAR();
    gemm_store(sA, sW, g_H0, nullptr, row0, N_MEM_C, wr, wc, l16, l4);
    SBAR();                               // all gemm reads of sW done
    gload_lin8(sW, g_WT + TIL(1), wid, lane);
    WAIT_VM0(); SBAR();
    gemm_store(sA, sW, g_Hvj, msg_b1, row0, N_MEM_C, wr, wc, l16, l4);
    SBAR();
    gload_lin8(sW, g_WT + TIL(4), wid, lane);
    WAIT_VM0(); SBAR();
    gemm_store(sA, sW, g_Hm, hid_b1, row0, N_MEM_C, wr, wc, l16, l4);
  } else {                                // uncon row-chunk -> U5
    int row0 = (bid - 512) * 128;
    gload_rows8(sA, g_ub, nullptr, row0, NNODES_C - 1, wid, lane);
    gload_lin8(sW, g_WT + TIL(5), wid, lane);
    WAIT_VM0(); SBAR();
    gemm_store(sA, sW, g_U5, nullptr, row0, 50048, wr, wc, l16, l4);
  }
}

// ===== K1: edge phase — T14 register prefetch pipeline over 4 tiles =====
extern "C" __global__ __launch_bounds__(256, 2) void edge_flow(
    const int* __restrict__ seen_edges, const float* __restrict__ msg_b2) {
  __shared__ u16 sH[64 * 128];      // 16 KB (swizzled)
  __shared__ u16 sW2[16384];        // 32 KB
  __shared__ int sEg[4][64], sRel[4][64], sVi[4][64];

  const int tid = threadIdx.x;
  const int lane = tid & 63, wid = tid >> 6;
  const int wr = wid >> 1, wc = wid & 1;     // 2x2 grid, 32x64 per wave
  const int l16 = lane & 15, l4 = lane >> 4;
  const int j0 = blockIdx.x * 64;
  const int pr = tid >> 2, pcs = (tid & 3) * 32;   // h-build ownership

  float mb2v[4];
#pragma unroll
  for (int nr = 0; nr < 4; ++nr) mb2v[nr] = msg_b2[wc * 64 + nr * 16 + l16];

  gload_lin4(sW2, g_WT + TIL(2), wid, lane);
  {
    int t = tid >> 6, r = tid & 63;
    int e = j0 + r + t * N_MEM_C;
    const int4* se = (const int4*)seen_edges + (size_t)e * 2;
    int4 lo = se[0], hi = se[1];
    sEg[t][r] = min(max(lo.x, 0), 63);
    sRel[t][r] = min(max(lo.w, 0), 499);
    sVi[t][r] = min(max(hi.z, 0), N_MEM_C - 1);
  }
  WAIT_LG0(); WAIT_VM0(); SBAR();       // W2 + indices resident

  const f32x4 zero4 = {0.f, 0.f, 0.f, 0.f};
  f32x4 aggr[2][4];
#pragma unroll
  for (int a = 0; a < 2; ++a)
#pragma unroll
    for (int b = 0; b < 4; ++b) aggr[a][b] = zero4;

  // t-invariant Hvj row (loaded once, held)
  uint4 vld[4];
  {
    const uint4* pv = (const uint4*)(g_Hvj + (size_t)(j0 + pr) * 128 + pcs);
#pragma unroll
    for (int m = 0; m < 4; ++m) vld[m] = pv[m];
  }
  // tile-0 prefetch
  uint4 hld[4];
  float4 rl[8], ql[8];
  {
    const uint4* p0 = (const uint4*)(g_H0 + (size_t)sVi[0][pr] * 128 + pcs);
    const float4* prl = (const float4*)(g_relW + sRel[0][pr] * 128 + pcs);
    const float4* pq = (const float4*)(g_qsumM + sEg[0][pr] * 128 + pcs);
#pragma unroll
    for (int m = 0; m < 4; ++m) hld[m] = p0[m];
#pragma unroll
    for (int m = 0; m < 8; ++m) { rl[m] = prl[m]; ql[m] = pq[m]; }
  }

#pragma unroll 1
  for (int t = 0; t < 4; ++t) {
    // build h = lrelu(H0[vi] + Hvj[j] + relW + qsumM) from PREFETCHED regs -> sH
#pragma unroll
    for (int m = 0; m < 4; ++m) {
      u16 h0[8], hv[8];
      __builtin_memcpy(h0, &hld[m], 16); __builtin_memcpy(hv, &vld[m], 16);
      float4 r0 = rl[2 * m], r1 = rl[2 * m + 1];
      float4 q0 = ql[2 * m], q1 = ql[2 * m + 1];
      float v[8];
      v[0] = bf2f(h0[0]) + bf2f(hv[0]) + r0.x + q0.x;
      v[1] = bf2f(h0[1]) + bf2f(hv[1]) + r0.y + q0.y;
      v[2] = bf2f(h0[2]) + bf2f(hv[2]) + r0.z + q0.z;
      v[3] = bf2f(h0[3]) + bf2f(hv[3]) + r0.w + q0.w;
      v[4] = bf2f(h0[4]) + bf2f(hv[4]) + r1.x + q1.x;
      v[5] = bf2f(h0[5]) + bf2f(hv[5]) + r1.y + q1.y;
      v[6] = bf2f(h0[6]) + bf2f(hv[6]) + r1.z + q1.z;
      v[7] = bf2f(h0[7]) + bf2f(hv[7]) + r1.w + q1.w;
#pragma unroll
      for (int p = 0; p < 8; ++p) v[p] = (v[p] >= 0.f) ? v[p] : 0.2f * v[p];
      *(uint4*)&sH[swz_off(pr, pcs + 8 * m)] =
          make_uint4(pk2(v[0], v[1]), pk2(v[2], v[3]), pk2(v[4], v[5]), pk2(v[6], v[7]));
    }
    // issue NEXT tile's gathers now — latency flies under gemm+tanh (T14)
    if (t < 3) {
      const uint4* p0 = (const uint4*)(g_H0 + (size_t)sVi[t + 1][pr] * 128 + pcs);
      const float4* prl = (const float4*)(g_relW + sRel[t + 1][pr] * 128 + pcs);
      const float4* pq = (const float4*)(g_qsumM + sEg[t + 1][pr] * 128 + pcs);
#pragma unroll
      for (int m = 0; m < 4; ++m) hld[m] = p0[m];
#pragma unroll
      for (int m = 0; m < 8; ++m) { rl[m] = prl[m]; ql[m] = pq[m]; }
    }
    WAIT_LG0(); SBAR();                  // h writes drained, published

    f32x4 acc2[2][4];
#pragma unroll
    for (int a = 0; a < 2; ++a)
#pragma unroll
      for (int b = 0; b < 4; ++b) acc2[a][b] = zero4;
    gemmS64(sH, sW2, acc2, wr, wc, l16, l4);
#pragma unroll
    for (int mr = 0; mr < 2; ++mr)
#pragma unroll
      for (int nr = 0; nr < 4; ++nr)
#pragma unroll
        for (int i = 0; i < 4; ++i)
          aggr[mr][nr][i] += fast_tanh(acc2[mr][nr][i] + mb2v[nr]);
    WAIT_LG0(); SBAR();                  // reads consumed before overwrite
  }

  // write aggr rows (bf16)
#pragma unroll
  for (int mr = 0; mr < 2; ++mr)
#pragma unroll
    for (int nr = 0; nr < 4; ++nr)
#pragma unroll
      for (int i = 0; i < 4; ++i) {
        int row = j0 + wr * 32 + mr * 16 + l4 * 4 + i;
        int col = wc * 64 + nr * 16 + l16;
        g_aggr[(size_t)row * 128 + col] = f2bf_s(aggr[mr][nr][i]);
      }
}

// ================= K2: update phase (unchanged r18) =================
extern "C" __global__ __launch_bounds__(512, 2) void update_flow(
    const int* __restrict__ memorized, const float* __restrict__ node_att,
    const float* __restrict__ hid_b2, float* __restrict__ out) {
  __shared__ u16 sA[16384], sH[16384];
  __shared__ u16 sW3[16384], sW2[16384];
  __shared__ int sMeg[128], sMvm[128];
  __shared__ float sNA[128];

  const int tid = threadIdx.x;
  const int lane = tid & 63, wid = tid >> 6;
  const int wr = wid >> 2, wc = wid & 3;
  const int l16 = lane & 15, l4 = lane >> 4;
  const int j0 = blockIdx.x * 128;

  float hb2v[2];
#pragma unroll
  for (int nr = 0; nr < 2; ++nr) hb2v[nr] = hid_b2[wc * 32 + nr * 16 + l16];

  gload_rows8(sA, g_aggr, nullptr, j0, N_MEM_C - 1, wid, lane);
  gload_lin8(sW3, g_WT + TIL(3), wid, lane);
  gload_lin8(sW2, g_WT + TIL(6), wid, lane);
  if (tid < 128) {
    int2 mn = ((const int2*)memorized)[j0 + tid];
    int eg = min(max(mn.x, 0), 63);
    int vm = min(max(mn.y, 0), NNODES_C - 1);
    sMeg[tid] = eg; sMvm[tid] = vm;
    sNA[tid] = node_att[(size_t)eg * NNODES_C + vm];
  }
  WAIT_LG0(); WAIT_VM0(); SBAR();

  const f32x4 zero4 = {0.f, 0.f, 0.f, 0.f};
  f32x4 accU[4][2];
#pragma unroll
  for (int a = 0; a < 4; ++a)
#pragma unroll
    for (int b = 0; b < 2; ++b) accU[a][b] = zero4;
  gemmS128(sA, sW3, accU, wr, wc, l16, l4);    // aggr @ (0.5*hidW1_aggr)

#pragma unroll
  for (int mr = 0; mr < 4; ++mr)
#pragma unroll
    for (int i = 0; i < 4; ++i) {
      int r = wr * 64 + mr * 16 + l4 * 4 + i;
      float na = sNA[r];
      const u16* pM = g_Hm + (size_t)(j0 + r) * 128;
      const u16* pU = g_U5 + (size_t)sMvm[r] * 128;
      const float* pQ = g_qsumH + sMeg[r] * 128;
#pragma unroll
      for (int nr = 0; nr < 2; ++nr) {
        int c = wc * 32 + nr * 16 + l16;
        accU[mr][nr][i] += bf2f(pM[c]) + na * bf2f(pU[c]) + pQ[c];
      }
    }
#pragma unroll
  for (int mr = 0; mr < 4; ++mr)
#pragma unroll
    for (int nr = 0; nr < 2; ++nr)
#pragma unroll
      for (int i = 0; i < 4; ++i) {
        float v = accU[mr][nr][i];
        v = (v >= 0.f) ? v : 0.2f * v;
        int r = wr * 64 + mr * 16 + l4 * 4 + i;
        sH[swz_off(r, wc * 32 + nr * 16 + l16)] = f2bf_s(v);
      }
  WAIT_LG0(); SBAR();

  f32x4 accF[4][2];
#pragma unroll
  for (int a = 0; a < 4; ++a)
#pragma unroll
    for (int b = 0; b < 2; ++b) accF[a][b] = zero4;
  gemmS128(sH, sW2, accF, wr, wc, l16, l4);

#pragma unroll
  for (int mr = 0; mr < 4; ++mr)
#pragma unroll
    for (int nr = 0; nr < 2; ++nr)
#pragma unroll
      for (int i = 0; i < 4; ++i) {
        int row = j0 + wr * 64 + mr * 16 + l4 * 4 + i;
        int col = wc * 32 + nr * 16 + l16;
        size_t o = (size_t)row * DDIM + col;
        out[o] = bf2f(g_hb[o]) + fast_tanh(accF[mr][nr][i] + hb2v[nr]);
      }
}

extern "C" void kernel_launch(void* const* d_in, const int* in_sizes, int n_in,
                              void* d_out, int out_size, void* d_ws, size_t ws_size,
                              hipStream_t stream) {
  (void)in_sizes; (void)n_in; (void)out_size; (void)d_ws; (void)ws_size;
  const float* hidden       = (const float*)d_in[0];
  const int*   seen_edges   = (const int*)d_in[1];
  const int*   memorized    = (const int*)d_in[2];
  const float* node_att     = (const float*)d_in[3];
  const float* hidden_uncon = (const float*)d_in[4];
  const float* qh           = (const float*)d_in[5];
  const float* qr           = (const float*)d_in[6];
  const float* rel_table    = (const float*)d_in[7];
  const float* msg_W1       = (const float*)d_in[8];
  const float* msg_b1       = (const float*)d_in[9];
  const float* msg_W2       = (const float*)d_in[10];
  const float* msg_b2       = (const float*)d_in[11];
  const float* hid_W1       = (const float*)d_in[12];
  const float* hid_b1       = (const float*)d_in[13];
  const float* hid_W2       = (const float*)d_in[14];
  const float* hid_b2       = (const float*)d_in[15];
  const float* int_W        = (const float*)d_in[16];

  prep_all<<<dim3(7951), dim3(256), 0, stream>>>(
      hidden, hidden_uncon, msg_W1, msg_W2, hid_W1, hid_W2, int_W,
      rel_table, qh, qr);
  prep_tables<<<dim3(903), dim3(512), 0, stream>>>(msg_b1, hid_b1);
  edge_flow<<<dim3(N_MEM_C / 64), dim3(256), 0, stream>>>(seen_edges, msg_b2);
  update_flow<<<dim3(N_MEM_C / 128), dim3(512), 0, stream>>>(
      memorized, node_att, hid_b2, (float*)d_out);
}

// Round 20
// 117.319 us; speedup vs baseline: 1.3797x; 1.2096x over previous
//
#include <hip/hip_runtime.h>
#include <hip/hip_bf16.h>

typedef unsigned short u16;
typedef __attribute__((ext_vector_type(8))) short bf16x8;
typedef __attribute__((ext_vector_type(4))) float f32x4;

#define N_MEM_C 65536
#define NNODES_C 50000
#define DDIM 128
#define BM 128
#define NTHR 512
#define TIL(t) ((t) * 16384)

// bf16 [n][k] weight tiles (128x128), stored PRE-SWIZZLED (XOR of 16B-granule
// index with row&7) so a linear global_load_lds yields the swizzled LDS image:
// 0: msg_W1[0:128]^T (vi)   1: msg_W1[256:384]^T (vj)   2: msg_W2^T
// 3: hid_W1[0:128]^T (aggr) 4: hid_W1[128:256]^T (hidden)
// 5: (int_W @ hid_W1[256:384])^T    6: hid_W2^T
__device__ __align__(16) u16 g_WT[7 * 16384];
__device__ __align__(16) float g_relW[500 * 128];   // rel_table @ msg_W1[128:256]
__device__ __align__(16) float g_qsumM[64 * 128];
__device__ __align__(16) float g_qsumH[64 * 128];
// bf16 copies of hidden / hidden_uncon (row-major, NOT swizzled; gathers
// apply the swizzle on the per-lane global address)
__device__ __align__(16) u16 g_hb[(size_t)N_MEM_C * DDIM];
__device__ __align__(16) u16 g_ub[(size_t)NNODES_C * DDIM];

#define SBAR() do { asm volatile("" ::: "memory"); __builtin_amdgcn_s_barrier(); \
                    asm volatile("" ::: "memory"); } while (0)
#define WAIT_VM0() asm volatile("s_waitcnt vmcnt(0)" ::: "memory")
#define WAIT_VM4() asm volatile("s_waitcnt vmcnt(4)" ::: "memory")
#define WAIT_LG0() asm volatile("s_waitcnt lgkmcnt(0)" ::: "memory")

__device__ __forceinline__ u16 f2bf_s(float f) {
  __hip_bfloat16 h = __float2bfloat16(f);
  u16 u; __builtin_memcpy(&u, &h, 2);
  return u;
}
__device__ __forceinline__ unsigned pk2(float a, float b) {
  __hip_bfloat162 h = __float22bfloat162_rn(make_float2(a, b));
  unsigned u; __builtin_memcpy(&u, &h, 4);
  return u;
}
__device__ __forceinline__ float bf2f(u16 u) {
  unsigned v = ((unsigned)u) << 16;
  float f; __builtin_memcpy(&f, &v, 4);
  return f;
}
__device__ __forceinline__ float fast_tanh(float x) {
  float e = __expf(2.0f * x);
  return 1.0f - 2.0f / (e + 1.0f);
}
__device__ __forceinline__ int swz_off(int r, int c) {
  return r * 128 + ((((c >> 3) ^ (r & 7)) << 3) | (c & 7));
}

// ================= merged prep kernel (single launch) =================
// block ranges: [0,7221) conv | [7221,7605) wt(swz) | [7605,7669) weff(swz)
//               [7669,7919) relW | [7919,7951) qsum
extern "C" __global__ void prep_all(const float* __restrict__ hidden,
                                    const float* __restrict__ uncon,
                                    const float* __restrict__ msg_W1,
                                    const float* __restrict__ msg_W2,
                                    const float* __restrict__ hid_W1,
                                    const float* __restrict__ hid_W2,
                                    const float* __restrict__ int_W,
                                    const float* __restrict__ rel_table,
                                    const float* __restrict__ qh,
                                    const float* __restrict__ qr) {
  int bid = blockIdx.x;
  if (bid < 7221) {                       // f32 -> bf16 copies (octets of 8)
    const size_t NH = (size_t)N_MEM_C * DDIM / 8;
    size_t i = (size_t)bid * 256 + threadIdx.x;
    const float* src; u16* dst; size_t o;
    if (i < NH) { src = hidden; dst = g_hb; o = i; }
    else { src = uncon; dst = g_ub; o = i - NH; }
    const float4* p = (const float4*)(src + o * 8);
    float4 a = p[0], b = p[1];
    *(uint4*)(dst + o * 8) =
        make_uint4(pk2(a.x, a.y), pk2(a.z, a.w), pk2(b.x, b.y), pk2(b.z, b.w));
  } else if (bid < 7605) {                // transpose+convert+SWIZZLE 6 tiles
    int i = (bid - 7221) * 256 + threadIdx.x;
    int t = i >> 14, idx = i & 16383;
    int n = idx >> 7, k = idx & 127;
    const float* src; int dst;
    switch (t) {
      case 0:  src = msg_W1;             dst = TIL(0); break;
      case 1:  src = msg_W1 + 256 * 128; dst = TIL(1); break;
      case 2:  src = msg_W2;             dst = TIL(2); break;
      case 3:  src = hid_W1;             dst = TIL(3); break;
      case 4:  src = hid_W1 + 128 * 128; dst = TIL(4); break;
      default: src = hid_W2;             dst = TIL(6); break;
    }
    g_WT[dst + swz_off(n, k)] = f2bf_s(src[k * 128 + n]);
  } else if (bid < 7669) {                // Weff = int_W @ hid_W1[256:384] (swz)
    int i = (bid - 7605) * 256 + threadIdx.x;
    int n = i & 127, q = i >> 7;
    float s = 0.f;
    for (int p = 0; p < 128; ++p)
      s += int_W[q * 128 + p] * hid_W1[(256 + p) * 128 + n];
    g_WT[TIL(5) + swz_off(n, q)] = f2bf_s(s);
  } else if (bid < 7919) {                // relW
    int i = (bid - 7669) * 256 + threadIdx.x;
    int r = i >> 7, n = i & 127;
    float s = 0.f;
    for (int k = 0; k < 128; ++k)
      s += rel_table[r * 128 + k] * msg_W1[(128 + k) * 128 + n];
    g_relW[i] = s;
  } else {                                // qsum (both MLPs)
    int i = (bid - 7919) * 256 + threadIdx.x;
    int g = i >> 7, n = i & 127;
    float sM = 0.f, sH = 0.f;
    for (int k = 0; k < 128; ++k) {
      float h = qh[g * 128 + k], r = qr[g * 128 + k];
      sM += h * msg_W1[(384 + k) * 128 + n] + r * msg_W1[(512 + k) * 128 + n];
      sH += h * hid_W1[(384 + k) * 128 + n] + r * hid_W1[(512 + k) * 128 + n];
    }
    g_qsumM[i] = sM;
    g_qsumH[i] = sH;
  }
}

// ---- async staging via global_load_lds (8 waves: 4 issues/wave) ----
__device__ __forceinline__ void gload_rows(u16* lds_tile, const u16* __restrict__ gsrc,
                                           const int* idxArr, int base,
                                           int wid, int lane) {
  int rsub = lane >> 4, s = lane & 15;
#pragma unroll
  for (int k = 0; k < 4; ++k) {
    int r = wid * 16 + k * 4 + rsub;
    int idx = idxArr ? idxArr[r] : (base + r);
    const u16* gp = gsrc + (size_t)idx * DDIM + ((s ^ (r & 7)) << 3);
    u16* lp = lds_tile + (wid * 16 + k * 4) * 128;   // wave-uniform base
    __builtin_amdgcn_global_load_lds((const __attribute__((address_space(1))) void*)gp,
                                     (__attribute__((address_space(3))) void*)lp,
                                     16, 0, 0);
  }
}
__device__ __forceinline__ void gload_lin(u16* lds_tile, const u16* __restrict__ gsrc,
                                          int wid, int lane) {
#pragma unroll
  for (int k = 0; k < 4; ++k) {
    int off = (wid * 4 + k) * 512;
    const u16* gp = gsrc + off + lane * 8;
    u16* lp = lds_tile + off;
    __builtin_amdgcn_global_load_lds((const __attribute__((address_space(1))) void*)gp,
                                     (__attribute__((address_space(3))) void*)lp,
                                     16, 0, 0);
  }
}

// acc += A(128x128 swz LDS) @ W(128x128 swz LDS)^T ; wave tile 64x32 (2x4 grid)
__device__ __forceinline__ void gemmS(const u16* A, const u16* W,
                                      f32x4 (&acc)[4][2], int wr, int wc, int l16, int l4) {
#pragma unroll
  for (int ks = 0; ks < 4; ++ks) {
    int gsl = ks * 4 + l4;
    bf16x8 av[4], bv[2];
#pragma unroll
    for (int nr = 0; nr < 2; ++nr) {
      int rW = wc * 32 + nr * 16 + l16;
      bv[nr] = *(const bf16x8*)&W[rW * 128 + ((gsl ^ (rW & 7)) << 3)];
    }
#pragma unroll
    for (int mr = 0; mr < 4; ++mr) {
      int rA = wr * 64 + mr * 16 + l16;
      av[mr] = *(const bf16x8*)&A[rA * 128 + ((gsl ^ (rA & 7)) << 3)];
    }
#pragma unroll
    for (int mr = 0; mr < 4; ++mr)
#pragma unroll
      for (int nr = 0; nr < 2; ++nr)
        acc[mr][nr] = __builtin_amdgcn_mfma_f32_16x16x32_bf16(av[mr], bv[nr], acc[mr][nr], 0, 0, 0);
  }
}

extern "C" __global__ __launch_bounds__(NTHR, 2) void fused_flow(
    const int* __restrict__ seen_edges, const int* __restrict__ memorized,
    const float* __restrict__ node_att,
    const float* __restrict__ msg_b1, const float* __restrict__ msg_b2,
    const float* __restrict__ hid_b1, const float* __restrict__ hid_b2,
    float* __restrict__ out) {
  __shared__ u16 sA0[16384], sA1[16384];   // A-tile double buffer (swizzled)
  __shared__ u16 sW0b[16384], sW2b[16384]; // W tiles (swizzled)
  __shared__ int sEg[4][BM], sRel[4][BM], sVi[4][BM];
  __shared__ int sMeg[BM], sMvm[BM];
  __shared__ float sNA[BM];

  const int tid = threadIdx.x;
  const int lane = tid & 63, wid = tid >> 6;
  const int wr = wid >> 2, wc = wid & 3;   // 2x4 wave grid, 64x32 per wave
  const int l16 = lane & 15, l4 = lane >> 4;
  const int j0 = blockIdx.x * BM;

  float mb1v[2], mb2v[2], hb1v[2], hb2v[2];
#pragma unroll
  for (int nr = 0; nr < 2; ++nr) {
    int col = wc * 32 + nr * 16 + l16;
    mb1v[nr] = msg_b1[col]; mb2v[nr] = msg_b2[col];
    hb1v[nr] = hid_b1[col]; hb2v[nr] = hid_b2[col];
  }

  // ---- prologue: W0<-vi-tile, W2<-vj-tile, sA0<-vj rows; index staging ----
  gload_lin(sW0b, g_WT + TIL(0), wid, lane);
  gload_lin(sW2b, g_WT + TIL(1), wid, lane);
  gload_rows(sA0, g_hb, nullptr, j0, wid, lane);
  {
    int t = tid >> 7, r = tid & 127;
    int e = j0 + r + t * N_MEM_C;
    const int4* se = (const int4*)seen_edges + (size_t)e * 2;
    int4 lo = se[0], hi = se[1];
    sEg[t][r] = min(max(lo.x, 0), 63);
    sRel[t][r] = min(max(lo.w, 0), 499);
    sVi[t][r] = min(max(hi.z, 0), N_MEM_C - 1);
  }
  if (tid < BM) {
    int2 mn = ((const int2*)memorized)[j0 + tid];
    int eg = min(max(mn.x, 0), 63);
    int vm = min(max(mn.y, 0), NNODES_C - 1);
    sMeg[tid] = eg; sMvm[tid] = vm;
    sNA[tid] = node_att[(size_t)eg * NNODES_C + vm];
  }
  WAIT_LG0(); SBAR();                       // indices visible
  gload_rows(sA1, g_hb, sVi[0], 0, wid, lane);   // A(0)
  WAIT_VM0(); SBAR();                       // W0, Wvj, vj-tile, A(0) resident

  const f32x4 zero4 = {0.f, 0.f, 0.f, 0.f};
  f32x4 acc_vj[4][2], aggr[4][2];
#pragma unroll
  for (int a = 0; a < 4; ++a)
#pragma unroll
    for (int b = 0; b < 2; ++b) { acc_vj[a][b] = zero4; aggr[a][b] = zero4; }
  gemmS(sA0, sW2b, acc_vj, wr, wc, l16, l4);     // vj chunk (shared by all tiles)
  SBAR();                                   // sA0 / sW2b free
  gload_lin(sW2b, g_WT + TIL(2), wid, lane);     // msg_W2
  gload_rows(sA0, g_hb, sVi[1], 0, wid, lane);   // A(1)

  // ---- edge loop; A(t) in (t even ? sA1 : sA0) ----
#pragma unroll 1
  for (int t = 0; t < 4; ++t) {
    u16* Acur = (t & 1) ? sA0 : sA1;
    f32x4 acc[4][2];
#pragma unroll
    for (int a = 0; a < 4; ++a)
#pragma unroll
      for (int b = 0; b < 2; ++b) acc[a][b] = acc_vj[a][b];
    gemmS(Acur, sW0b, acc, wr, wc, l16, l4);     // vi chunk

    // gather-add: rel + query contributions (f32 tables, L2-hot)
#pragma unroll
    for (int mr = 0; mr < 4; ++mr)
#pragma unroll
      for (int i = 0; i < 4; ++i) {
        int r = wr * 64 + mr * 16 + l4 * 4 + i;
        const float* pr = g_relW + sRel[t][r] * 128;
        const float* pq = g_qsumM + sEg[t][r] * 128;
#pragma unroll
        for (int nr = 0; nr < 2; ++nr) {
          int c = wc * 32 + nr * 16 + l16;
          acc[mr][nr][i] += pr[c] + pq[c];
        }
      }
    SBAR();                                 // B1: all waves done reading A(t)

    // h = leaky_relu(acc + b1) -> Acur (swizzled)
#pragma unroll
    for (int mr = 0; mr < 4; ++mr)
#pragma unroll
      for (int nr = 0; nr < 2; ++nr)
#pragma unroll
        for (int i = 0; i < 4; ++i) {
          float v = acc[mr][nr][i] + mb1v[nr];
          v = (v >= 0.f) ? v : 0.2f * v;
          int r = wr * 64 + mr * 16 + l4 * 4 + i;
          Acur[swz_off(r, wc * 32 + nr * 16 + l16)] = f2bf_s(v);
        }
    WAIT_LG0();
    if (t == 0) { WAIT_VM4(); }             // drain msg_W2 (oldest), keep A(1)
    SBAR();                                 // B2: h visible (+W2 at t=0)

    f32x4 acc2[4][2];
#pragma unroll
    for (int a = 0; a < 4; ++a)
#pragma unroll
      for (int b = 0; b < 2; ++b) acc2[a][b] = zero4;
    gemmS(Acur, sW2b, acc2, wr, wc, l16, l4);    // h @ msg_W2
#pragma unroll
    for (int mr = 0; mr < 4; ++mr)
#pragma unroll
      for (int nr = 0; nr < 2; ++nr)
#pragma unroll
        for (int i = 0; i < 4; ++i)
          aggr[mr][nr][i] += fast_tanh(acc2[mr][nr][i] + mb2v[nr]);
    WAIT_VM0();                             // A(t+1) LDS writes complete
    SBAR();                                 // B3: visible to all waves; Acur free
    if (t < 2)
      gload_rows(Acur, g_hb, sVi[t + 2], 0, wid, lane);   // A(t+2) -> Acur
  }

  // ---- update phase. sA0 = h(3) dead, sA1 = h(2) dead ----
  gload_lin(sW0b, g_WT + TIL(3), wid, lane);     // hid_W1 aggr chunk
  gload_lin(sW2b, g_WT + TIL(4), wid, lane);     // hid_W1 hidden chunk
  gload_rows(sA0, g_hb, nullptr, j0, wid, lane); // hidden[m] rows
  // aggr tile (0.5 * aggr) -> sA1 (swizzled)
#pragma unroll
  for (int mr = 0; mr < 4; ++mr)
#pragma unroll
    for (int nr = 0; nr < 2; ++nr)
#pragma unroll
      for (int i = 0; i < 4; ++i) {
        int r = wr * 64 + mr * 16 + l4 * 4 + i;
        sA1[swz_off(r, wc * 32 + nr * 16 + l16)] = f2bf_s(0.5f * aggr[mr][nr][i]);
      }
  WAIT_LG0(); WAIT_VM0(); SBAR();

  f32x4 accU[4][2];
#pragma unroll
  for (int a = 0; a < 4; ++a)
#pragma unroll
    for (int b = 0; b < 2; ++b) accU[a][b] = zero4;
  gemmS(sA1, sW0b, accU, wr, wc, l16, l4);       // aggr chunk
  SBAR();                                   // sW0b, sA1 free
  gload_lin(sW0b, g_WT + TIL(5), wid, lane);     // Weff
  gload_rows(sA1, g_ub, sMvm, 0, wid, lane);     // uncon rows (unscaled)
  gemmS(sA0, sW2b, accU, wr, wc, l16, l4);       // hidden chunk
  SBAR();                                   // sW2b free
  gload_lin(sW2b, g_WT + TIL(6), wid, lane);     // hid_W2
  WAIT_VM4(); SBAR();                       // Weff + uncon resident; W2 in flight

  f32x4 acc2[4][2];
#pragma unroll
  for (int a = 0; a < 4; ++a)
#pragma unroll
    for (int b = 0; b < 2; ++b) acc2[a][b] = zero4;
  gemmS(sA1, sW0b, acc2, wr, wc, l16, l4);       // uncon @ Weff (unscaled rows)
#pragma unroll
  for (int mr = 0; mr < 4; ++mr)
#pragma unroll
    for (int i = 0; i < 4; ++i) {
      int r = wr * 64 + mr * 16 + l4 * 4 + i;
      float na = sNA[r];
      const float* pq = g_qsumH + sMeg[r] * 128;
#pragma unroll
      for (int nr = 0; nr < 2; ++nr)
        accU[mr][nr][i] += na * acc2[mr][nr][i] + pq[wc * 32 + nr * 16 + l16];
    }
  // h -> sA0 (its readers finished before previous barriers)
#pragma unroll
  for (int mr = 0; mr < 4; ++mr)
#pragma unroll
    for (int nr = 0; nr < 2; ++nr)
#pragma unroll
      for (int i = 0; i < 4; ++i) {
        float v = accU[mr][nr][i] + hb1v[nr];
        v = (v >= 0.f) ? v : 0.2f * v;
        int r = wr * 64 + mr * 16 + l4 * 4 + i;
        sA0[swz_off(r, wc * 32 + nr * 16 + l16)] = f2bf_s(v);
      }
  WAIT_LG0(); WAIT_VM0(); SBAR();           // h visible, hid_W2 resident

  f32x4 accF[4][2];
#pragma unroll
  for (int a = 0; a < 4; ++a)
#pragma unroll
    for (int b = 0; b < 2; ++b) accF[a][b] = zero4;
  gemmS(sA0, sW2b, accF, wr, wc, l16, l4);

#pragma unroll
  for (int mr = 0; mr < 4; ++mr)
#pragma unroll
    for (int nr = 0; nr < 2; ++nr)
#pragma unroll
      for (int i = 0; i < 4; ++i) {
        int row = j0 + wr * 64 + mr * 16 + l4 * 4 + i;
        int col = wc * 32 + nr * 16 + l16;
        size_t o = (size_t)row * DDIM + col;
        out[o] = bf2f(g_hb[o]) + fast_tanh(accF[mr][nr][i] + hb2v[nr]);
      }
}

extern "C" void kernel_launch(void* const* d_in, const int* in_sizes, int n_in,
                              void* d_out, int out_size, void* d_ws, size_t ws_size,
                              hipStream_t stream) {
  (void)in_sizes; (void)n_in; (void)out_size; (void)d_ws; (void)ws_size;
  const float* hidden       = (const float*)d_in[0];
  const int*   seen_edges   = (const int*)d_in[1];
  const int*   memorized    = (const int*)d_in[2];
  const float* node_att     = (const float*)d_in[3];
  const float* hidden_uncon = (const float*)d_in[4];
  const float* qh           = (const float*)d_in[5];
  const float* qr           = (const float*)d_in[6];
  const float* rel_table    = (const float*)d_in[7];
  const float* msg_W1       = (const float*)d_in[8];
  const float* msg_b1       = (const float*)d_in[9];
  const float* msg_W2       = (const float*)d_in[10];
  const float* msg_b2       = (const float*)d_in[11];
  const float* hid_W1       = (const float*)d_in[12];
  const float* hid_b1       = (const float*)d_in[13];
  const float* hid_W2       = (const float*)d_in[14];
  const float* hid_b2       = (const float*)d_in[15];
  const float* int_W        = (const float*)d_in[16];

  prep_all<<<dim3(7951), dim3(256), 0, stream>>>(
      hidden, hidden_uncon, msg_W1, msg_W2, hid_W1, hid_W2, int_W,
      rel_table, qh, qr);
  fused_flow<<<dim3(N_MEM_C / BM), dim3(NTHR), 0, stream>>>(
      seen_edges, memorized, node_att, msg_b1, msg_b2, hid_b1, hid_b2, (float*)d_out);
}